// Round 14
// baseline (136.057 us; speedup 1.0000x reference)
//
#include <hip/hip_runtime.h>
#include <hip/hip_bf16.h>

#define D_MODEL 1024
#define NHEADS  16
#define HDIM    64
#define SEQ     2048
#define BATCH   2
#define MROWS   (BATCH * SEQ)   // 4096
#define CHELEM  ((size_t)BATCH * NHEADS * SEQ * HDIM)  // 4194304

typedef __bf16 bf16x8 __attribute__((ext_vector_type(8)));
typedef float  f32x4  __attribute__((ext_vector_type(4)));

__device__ __forceinline__ unsigned short f2bf(float f) {
  unsigned u = __builtin_bit_cast(unsigned, f);
  return (unsigned short)((u + 0x7fffu + ((u >> 16) & 1u)) >> 16);
}

__device__ __forceinline__ float fexp2(float x) {
#if __has_builtin(__builtin_amdgcn_exp2f)
  return __builtin_amdgcn_exp2f(x);
#else
  return __expf(x * 0.6931471805599453f);
#endif
}

__device__ __forceinline__ f32x4 mfma16(bf16x8 a, bf16x8 b, f32x4 c) {
  return __builtin_amdgcn_mfma_f32_16x16x32_bf16(a, b, c, 0, 0, 0);
}

__device__ __forceinline__ void gll16(const unsigned short* g, unsigned short* l) {
  __builtin_amdgcn_global_load_lds(
      (const __attribute__((address_space(1))) unsigned*)g,
      (__attribute__((address_space(3))) unsigned*)l, 16, 0, 0);
}

__global__ void cvt_f32_bf16(const float* __restrict__ in,
                             unsigned short* __restrict__ out, int n4) {
  int i = blockIdx.x * blockDim.x + threadIdx.x;
  if (i >= n4) return;
  float4 v = reinterpret_cast<const float4*>(in)[i];
  ushort4 o;
  o.x = f2bf(v.x); o.y = f2bf(v.y); o.z = f2bf(v.z); o.w = f2bf(v.w);
  reinterpret_cast<ushort4*>(out)[i] = o;
}

// fused conversion of the 4 weight matrices (saves 3 launches)
__global__ void cvt_w4(const float* __restrict__ s0, const float* __restrict__ s1,
                       const float* __restrict__ s2, const float* __restrict__ s3,
                       unsigned short* __restrict__ d0, unsigned short* __restrict__ d1,
                       unsigned short* __restrict__ d2, unsigned short* __restrict__ d3) {
  int i = blockIdx.x * blockDim.x + threadIdx.x;  // n4 = D*D/4
  const int y = blockIdx.y;
  const float* s = (y == 0) ? s0 : (y == 1) ? s1 : (y == 2) ? s2 : s3;
  unsigned short* d = (y == 0) ? d0 : (y == 1) ? d1 : (y == 2) ? d2 : d3;
  float4 v = reinterpret_cast<const float4*>(s)[i];
  ushort4 o;
  o.x = f2bf(v.x); o.y = f2bf(v.y); o.z = f2bf(v.z); o.w = f2bf(v.w);
  reinterpret_cast<ushort4*>(d)[i] = o;
}

// C = A[M,K] * Bt[N,K]^T + bias  (global_load_lds staging, m97 pattern)
// MODE 2: out f32 row-major [M,N]  (final projection, bias=b0)
// MODE 3: fused QKV: N=3072; chunk 0->Q [B,H,S,64] (PRE-SCALED by
//         0.125*log2e for exp2-domain softmax), 1->K, 2->V^T [B,H,64,S]
template <int MODE>
__global__ __launch_bounds__(256) void gemm_bt2(
    const unsigned short* __restrict__ A,
    const unsigned short* __restrict__ Bt,
    const float* __restrict__ b0, const float* __restrict__ b1,
    const float* __restrict__ b2,
    void* __restrict__ outp, int M, int N, int K) {
  __shared__ __align__(16) unsigned short lA[128 * 32];
  __shared__ __align__(16) unsigned short lB[128 * 32];
  const int tid = threadIdx.x;
  const int m0 = blockIdx.y * 128, n0 = blockIdx.x * 128;
  const int lane = tid & 63, wid = tid >> 6;
  const int wr = wid >> 1, wc = wid & 1;
  const int fr = lane & 15, g = lane >> 4;

  const int srow = wid * 32 + (lane >> 2);
  const int scol = (lane & 3) * 8;
  const unsigned short* gA = A + (size_t)(m0 + srow) * K + scol;
  const unsigned short* gB = Bt + (size_t)(n0 + srow) * K + scol;
  unsigned short* lAw = lA + wid * 1024;
  unsigned short* lBw = lB + wid * 1024;

  f32x4 acc[4][4];
#pragma unroll
  for (int i = 0; i < 4; ++i)
#pragma unroll
    for (int j = 0; j < 4; ++j) acc[i][j] = (f32x4){0.f, 0.f, 0.f, 0.f};

  for (int kt = 0; kt < K; kt += 32) {
    gll16(gA + kt, lAw);
    gll16(gA + (size_t)16 * K + kt, lAw + 512);
    gll16(gB + kt, lBw);
    gll16(gB + (size_t)16 * K + kt, lBw + 512);
    __syncthreads();
    bf16x8 af[4], bfv[4];
#pragma unroll
    for (int i = 0; i < 4; ++i)
      af[i] = *reinterpret_cast<const bf16x8*>(
          &lA[(wr * 64 + i * 16 + fr) * 32 + g * 8]);
#pragma unroll
    for (int j = 0; j < 4; ++j)
      bfv[j] = *reinterpret_cast<const bf16x8*>(
          &lB[(wc * 64 + j * 16 + fr) * 32 + g * 8]);
#pragma unroll
    for (int i = 0; i < 4; ++i)
#pragma unroll
      for (int j = 0; j < 4; ++j)
        acc[i][j] = mfma16(af[i], bfv[j], acc[i][j]);
    __syncthreads();
  }

  const int src = n0 >> 10;
  const float* bp = (MODE == 2) ? b0 : (src == 0 ? b0 : (src == 1 ? b1 : b2));
#pragma unroll
  for (int i = 0; i < 4; ++i)
#pragma unroll
    for (int j = 0; j < 4; ++j)
#pragma unroll
      for (int r = 0; r < 4; ++r) {
        int m = m0 + wr * 64 + i * 16 + g * 4 + r;
        int n = n0 + wc * 64 + j * 16 + fr;
        if (MODE == 2) {
          float val = acc[i][j][r] + bp[n];
          reinterpret_cast<float*>(outp)[(size_t)m * N + n] = val;
        } else {
          int within = n & 1023;
          float val = acc[i][j][r] + bp[within];
          if (src == 0) val *= 0.1803368867f;  // 0.125 * log2(e)
          int b = m >> 11, s = m & 2047;
          int hh = within >> 6, dh = within & 63;
          size_t idx;
          if (src != 2)
            idx = ((size_t)(b * NHEADS + hh) * SEQ + s) * HDIM + dh;
          else
            idx = ((size_t)(b * NHEADS + hh) * HDIM + dh) * SEQ + s;
          reinterpret_cast<unsigned short*>(outp)[(size_t)src * CHELEM + idx] =
              f2bf(val);
        }
      }
}

// Flash attention, dual-chain unified loop: block j's two q-tile groups
// (4j+wid, nkt=j+1) and (124-4j+wid, nkt=32-j) share K/V tiles 0..j as a
// common prefix -> stage each tile ONCE, run both chains on it (2x ILP per
// barrier interval), tail runs chain B alone. Compute/block = 33 tile-steps
// for every block (balance preserved); staged tiles = 32-j (avg 24.5).
// bf16 P tile (0-conflict swizzle, proven) with compiler (__bf16) cast.
// Q,K: [B,H,S,64] bf16 ; Vt: [B,H,64,S] bf16 ; O: [B,S,1024] bf16
__global__ __launch_bounds__(256) void attn_fwd11(
    const unsigned short* __restrict__ Q,
    const unsigned short* __restrict__ Km,
    const unsigned short* __restrict__ Vt,
    unsigned short* __restrict__ O) {
  const int tid = threadIdx.x;
  const int lane = tid & 63, wid = tid >> 6;
  const int fr = lane & 15, g = lane >> 4;
  // XCD-grouped decode: lin%8 = XCD; 16 blocks per (b,h) slab on one XCD.
  const int lin = blockIdx.x;            // 0..511
  const int c = lin & 7;
  const int t = lin >> 3;                // 0..63
  const int j = t & 15;                  // block's pair index 0..15
  const int sgrp = t >> 4;               // 0..3
  const int slab = sgrp * 8 + c;         // 0..31
  const int b = slab >> 4, h = slab & 15;
  const int bh = b * NHEADS + h;

  __shared__ __align__(16) unsigned short lK[2][4096];   // 2 x 8KB, swizzled
  __shared__ __align__(16) unsigned short lV[2][4096];   // 2 x 8KB, swizzled
  __shared__ __align__(16) unsigned short plA[4][1024];  // P chain A, swizzled
  __shared__ __align__(16) unsigned short plB[4][1024];  // P chain B, swizzled
  char* plwA = reinterpret_cast<char*>(plA[wid]);
  char* plwB = reinterpret_cast<char*>(plB[wid]);

  const unsigned short* kptr = Km + (size_t)bh * SEQ * HDIM;
  const unsigned short* vptr = Vt + (size_t)bh * HDIM * SEQ;

  const int sr0 = tid >> 3;              // 0..31
  const int sch = tid & 7;
  const int schx = ((sch ^ (sr0 & 7)) << 3);  // elem offset of 16B chunk
  const int kswz0 = ((g ^ (fr & 7)) << 3);        // ch = g
  const int kswz1 = (((4 + g) ^ (fr & 7)) << 3);  // ch = 4+g

#define STAGE(BI, N0)                                                       \
  { gll16(kptr + (size_t)((N0) + sr0) * HDIM + schx, &lK[BI][wid * 512]);   \
    gll16(kptr + (size_t)((N0) + sr0 + 32) * HDIM + schx,                   \
          &lK[BI][2048 + wid * 512]);                                       \
    gll16(vptr + (size_t)sr0 * SEQ + (N0) + schx, &lV[BI][wid * 512]);      \
    gll16(vptr + (size_t)(sr0 + 32) * SEQ + (N0) + schx,                    \
          &lV[BI][2048 + wid * 512]); }

#define QKSTEP(QA0, QA1, S)                                                 \
  { _Pragma("unroll") for (int cc = 0; cc < 4; ++cc) {                      \
      S[cc] = (f32x4){0.f, 0.f, 0.f, 0.f};                                  \
      S[cc] = mfma16(QA0, kf0[cc], S[cc]);                                  \
      S[cc] = mfma16(QA1, kf1[cc], S[cc]);                                  \
    } }

#define SMAXP(S, MREG, LROW, OACC, MTILE, PLW, Q0, ISLAST, N0)              \
  { float sv[4][4];                                                         \
    float lmax = -3e30f;                                                    \
    if (ISLAST) {                                                           \
      _Pragma("unroll") for (int cc = 0; cc < 4; ++cc)                      \
      _Pragma("unroll") for (int r = 0; r < 4; ++r) {                       \
        sv[cc][r] = ((N0) + cc * 16 + fr <= (Q0) + g * 4 + r) ? S[cc][r]    \
                                                              : -1e30f;     \
        lmax = fmaxf(lmax, sv[cc][r]);                                      \
      }                                                                     \
    } else {                                                                \
      _Pragma("unroll") for (int cc = 0; cc < 4; ++cc)                      \
      _Pragma("unroll") for (int r = 0; r < 4; ++r) {                       \
        sv[cc][r] = S[cc][r];                                               \
        lmax = fmaxf(lmax, sv[cc][r]);                                      \
      }                                                                     \
    }                                                                       \
    if (!__all(lmax - MTILE <= 11.5f)) {                                    \
      _Pragma("unroll") for (int r = 0; r < 4; ++r) {                       \
        float tm = fmaxf(fmaxf(sv[0][r], sv[1][r]),                         \
                         fmaxf(sv[2][r], sv[3][r]));                        \
        _Pragma("unroll") for (int msk = 1; msk < 16; msk <<= 1)            \
            tm = fmaxf(tm, __shfl_xor(tm, msk, 64));                        \
        const float mn = fmaxf(MREG[r], tm);                                \
        const float al = fexp2(MREG[r] - mn);                               \
        MREG[r] = mn;                                                       \
        LROW[r] *= al;                                                      \
        _Pragma("unroll") for (int nf = 0; nf < 4; ++nf)                    \
            OACC[nf][r] *= al;                                              \
      }                                                                     \
      MTILE = fminf(fminf(MREG[0], MREG[1]), fminf(MREG[2], MREG[3]));      \
    }                                                                       \
    _Pragma("unroll") for (int r = 0; r < 4; ++r) {                         \
      const int rl = g * 4 + r;                                             \
      _Pragma("unroll") for (int cc = 0; cc < 4; ++cc) {                    \
        float p = fexp2(sv[cc][r] - MREG[r]);                               \
        LROW[r] += p;                                                       \
        int byte = (rl * 128 + (cc * 16 + fr) * 2) ^ ((rl & 7) << 4);       \
        *reinterpret_cast<unsigned short*>((PLW) + byte) =                  \
            __builtin_bit_cast(unsigned short, (__bf16)p);                  \
      }                                                                     \
    } }

#define PVSTEP(PLW, OACC)                                                   \
  { _Pragma("unroll") for (int blk = 0; blk < 2; ++blk) {                   \
      int byte = (fr * 128 + blk * 64 + g * 16) ^ ((fr & 7) << 4);          \
      bf16x8 pa = *reinterpret_cast<const bf16x8*>((PLW) + byte);           \
      _Pragma("unroll") for (int nf = 0; nf < 4; ++nf)                      \
          OACC[nf] = mfma16(pa, vfr[blk][nf], OACC[nf]);                    \
    } }

#define EPI(LROW, OACC, Q0)                                                 \
  { _Pragma("unroll") for (int r = 0; r < 4; ++r) {                         \
      float ls = LROW[r];                                                   \
      _Pragma("unroll") for (int msk = 1; msk < 16; msk <<= 1)              \
          ls += __shfl_xor(ls, msk, 64);                                    \
      const float inv = 1.f / ls;                                           \
      const size_t base =                                                   \
          ((size_t)b * SEQ + (Q0) + g * 4 + r) * D_MODEL + h * HDIM;        \
      _Pragma("unroll") for (int nf = 0; nf < 4; ++nf)                      \
          O[base + nf * 16 + fr] = f2bf(OACC[nf][r] * inv);                 \
    } }

  // chain A: q-tile 4j+wid (nktA=j+1); chain B: 124-4j+wid (nktB=32-j)
  const int qtA = 4 * j + wid, q0A = qtA * 16, nktA = j + 1;
  const int qtB = 124 - 4 * j + wid, q0B = qtB * 16, nktB = 32 - j;

  const unsigned short* qbA = Q + ((size_t)bh * SEQ + q0A + fr) * HDIM + g * 8;
  bf16x8 qaA0 = *reinterpret_cast<const bf16x8*>(qbA);
  bf16x8 qaA1 = *reinterpret_cast<const bf16x8*>(qbA + 32);
  const unsigned short* qbB = Q + ((size_t)bh * SEQ + q0B + fr) * HDIM + g * 8;
  bf16x8 qaB0 = *reinterpret_cast<const bf16x8*>(qbB);
  bf16x8 qaB1 = *reinterpret_cast<const bf16x8*>(qbB + 32);

  f32x4 oaccA[4], oaccB[4];
#pragma unroll
  for (int i = 0; i < 4; ++i) {
    oaccA[i] = (f32x4){0.f, 0.f, 0.f, 0.f};
    oaccB[i] = (f32x4){0.f, 0.f, 0.f, 0.f};
  }
  float mregA[4] = {-3e30f, -3e30f, -3e30f, -3e30f};
  float mregB[4] = {-3e30f, -3e30f, -3e30f, -3e30f};
  float lrowA[4] = {0.f, 0.f, 0.f, 0.f};
  float lrowB[4] = {0.f, 0.f, 0.f, 0.f};
  float mtileA = -3e30f, mtileB = -3e30f;

  STAGE(0, 0);
  __syncthreads();

  for (int kt = 0; kt < nktB; ++kt) {
    const int bi = kt & 1;
    if (kt + 1 < nktB) STAGE(bi ^ 1, (kt + 1) * 64);
    const int n0 = kt * 64;
    // K fragments (shared by both chains)
    bf16x8 kf0[4], kf1[4];
#pragma unroll
    for (int cc = 0; cc < 4; ++cc) {
      kf0[cc] = *reinterpret_cast<const bf16x8*>(
          &lK[bi][(cc * 16 + fr) * 64 + kswz0]);
      kf1[cc] = *reinterpret_cast<const bf16x8*>(
          &lK[bi][(cc * 16 + fr) * 64 + kswz1]);
    }
    // V fragments (shared by both chains)
    bf16x8 vfr[2][4];
#pragma unroll
    for (int blk = 0; blk < 2; ++blk) {
      const int vs = blk ? kswz1 : kswz0;
#pragma unroll
      for (int nf = 0; nf < 4; ++nf)
        vfr[blk][nf] = *reinterpret_cast<const bf16x8*>(
            &lV[bi][(nf * 16 + fr) * 64 + vs]);
    }
    const bool actA = (kt < nktA);  // uniform across block (nktA indep of wid)
    f32x4 sA[4], sB[4];
    if (actA) QKSTEP(qaA0, qaA1, sA);
    QKSTEP(qaB0, qaB1, sB);
    if (actA) SMAXP(sA, mregA, lrowA, oaccA, mtileA, plwA, q0A,
                    kt == nktA - 1, n0);
    SMAXP(sB, mregB, lrowB, oaccB, mtileB, plwB, q0B, kt == nktB - 1, n0);
    if (actA) PVSTEP(plwA, oaccA);
    PVSTEP(plwB, oaccB);
    __syncthreads();  // staged kt+1 complete; reads of buf bi done
  }

  EPI(lrowA, oaccA, q0A);
  EPI(lrowB, oaccB, q0B);
#undef STAGE
#undef QKSTEP
#undef SMAXP
#undef PVSTEP
#undef EPI
}

extern "C" void kernel_launch(void* const* d_in, const int* in_sizes, int n_in,
                              void* d_out, int out_size, void* d_ws,
                              size_t ws_size, hipStream_t stream) {
  const float* x  = (const float*)d_in[0];
  const float* wq = (const float*)d_in[1];
  const float* bq = (const float*)d_in[2];
  const float* wk = (const float*)d_in[3];
  const float* bk = (const float*)d_in[4];
  const float* wv = (const float*)d_in[5];
  const float* bv = (const float*)d_in[6];
  const float* wo = (const float*)d_in[7];
  const float* bo = (const float*)d_in[8];
  float* out = (float*)d_out;

  char* w = (char*)d_ws;
  unsigned short* xb    = (unsigned short*)w; w += (size_t)MROWS * D_MODEL * 2;
  unsigned short* wqkvb = (unsigned short*)w; w += (size_t)3 * D_MODEL * D_MODEL * 2;
  unsigned short* wob   = (unsigned short*)w; w += (size_t)D_MODEL * D_MODEL * 2;
  unsigned short* Qb    = (unsigned short*)w; w += CHELEM * 2 * 3;  // Q,K,Vt
  unsigned short* Ob    = (unsigned short*)w; w += (size_t)MROWS * D_MODEL * 2;
  unsigned short* Kb  = Qb + CHELEM;
  unsigned short* Vtb = Qb + 2 * CHELEM;

  {
    int n4 = MROWS * D_MODEL / 4;
    cvt_f32_bf16<<<n4 / 256, 256, 0, stream>>>(x, xb, n4);
  }
  {
    int n4 = D_MODEL * D_MODEL / 4;  // 262144 -> 1024 blocks x 4
    cvt_w4<<<dim3(n4 / 256, 4), 256, 0, stream>>>(
        wq, wk, wv, wo, wqkvb, wqkvb + (size_t)D_MODEL * D_MODEL,
        wqkvb + (size_t)2 * D_MODEL * D_MODEL, wob);
  }

  // fused QKV projection: N = 3072
  gemm_bt2<3><<<dim3(3 * D_MODEL / 128, MROWS / 128), 256, 0, stream>>>(
      xb, wqkvb, bq, bk, bv, Qb, MROWS, 3 * D_MODEL, D_MODEL);

  attn_fwd11<<<512, 256, 0, stream>>>(Qb, Kb, Vtb, Ob);

  gemm_bt2<2><<<dim3(D_MODEL / 128, MROWS / 128), 256, 0, stream>>>(
      Ob, wob, bo, bo, bo, out, MROWS, D_MODEL, D_MODEL);
}

// Round 15
// 128.369 us; speedup vs baseline: 1.0599x; 1.0599x over previous
//
#include <hip/hip_runtime.h>
#include <hip/hip_bf16.h>

#define D_MODEL 1024
#define NHEADS  16
#define HDIM    64
#define SEQ     2048
#define BATCH   2
#define MROWS   (BATCH * SEQ)   // 4096
#define CHELEM  ((size_t)BATCH * NHEADS * SEQ * HDIM)  // 4194304

typedef __bf16 bf16x8 __attribute__((ext_vector_type(8)));
typedef float  f32x4  __attribute__((ext_vector_type(4)));

__device__ __forceinline__ unsigned short f2bf(float f) {
  unsigned u = __builtin_bit_cast(unsigned, f);
  return (unsigned short)((u + 0x7fffu + ((u >> 16) & 1u)) >> 16);
}

__device__ __forceinline__ float fexp2(float x) {
#if __has_builtin(__builtin_amdgcn_exp2f)
  return __builtin_amdgcn_exp2f(x);
#else
  return __expf(x * 0.6931471805599453f);
#endif
}

__device__ __forceinline__ f32x4 mfma16(bf16x8 a, bf16x8 b, f32x4 c) {
  return __builtin_amdgcn_mfma_f32_16x16x32_bf16(a, b, c, 0, 0, 0);
}

__device__ __forceinline__ void gll16(const unsigned short* g, unsigned short* l) {
  __builtin_amdgcn_global_load_lds(
      (const __attribute__((address_space(1))) unsigned*)g,
      (__attribute__((address_space(3))) unsigned*)l, 16, 0, 0);
}

__global__ void cvt_f32_bf16(const float* __restrict__ in,
                             unsigned short* __restrict__ out, int n4) {
  int i = blockIdx.x * blockDim.x + threadIdx.x;
  if (i >= n4) return;
  float4 v = reinterpret_cast<const float4*>(in)[i];
  ushort4 o;
  o.x = f2bf(v.x); o.y = f2bf(v.y); o.z = f2bf(v.z); o.w = f2bf(v.w);
  reinterpret_cast<ushort4*>(out)[i] = o;
}

// fused conversion of the 4 weight matrices (saves 3 launches)
__global__ void cvt_w4(const float* __restrict__ s0, const float* __restrict__ s1,
                       const float* __restrict__ s2, const float* __restrict__ s3,
                       unsigned short* __restrict__ d0, unsigned short* __restrict__ d1,
                       unsigned short* __restrict__ d2, unsigned short* __restrict__ d3) {
  int i = blockIdx.x * blockDim.x + threadIdx.x;  // n4 = D*D/4
  const int y = blockIdx.y;
  const float* s = (y == 0) ? s0 : (y == 1) ? s1 : (y == 2) ? s2 : s3;
  unsigned short* d = (y == 0) ? d0 : (y == 1) ? d1 : (y == 2) ? d2 : d3;
  float4 v = reinterpret_cast<const float4*>(s)[i];
  ushort4 o;
  o.x = f2bf(v.x); o.y = f2bf(v.y); o.z = f2bf(v.z); o.w = f2bf(v.w);
  reinterpret_cast<ushort4*>(d)[i] = o;
}

// C = A[M,K] * Bt[N,K]^T + bias  (global_load_lds staging, m97 pattern)
// MODE 2: out f32 row-major [M,N]  (final projection, bias=b0)
// MODE 3: fused QKV: N=3072; chunk 0->Q [B,H,S,64] (PRE-SCALED by
//         0.125*log2e for exp2-domain softmax), 1->K, 2->V^T [B,H,64,S]
template <int MODE>
__global__ __launch_bounds__(256) void gemm_bt2(
    const unsigned short* __restrict__ A,
    const unsigned short* __restrict__ Bt,
    const float* __restrict__ b0, const float* __restrict__ b1,
    const float* __restrict__ b2,
    void* __restrict__ outp, int M, int N, int K) {
  __shared__ __align__(16) unsigned short lA[128 * 32];
  __shared__ __align__(16) unsigned short lB[128 * 32];
  const int tid = threadIdx.x;
  const int m0 = blockIdx.y * 128, n0 = blockIdx.x * 128;
  const int lane = tid & 63, wid = tid >> 6;
  const int wr = wid >> 1, wc = wid & 1;
  const int fr = lane & 15, g = lane >> 4;

  const int srow = wid * 32 + (lane >> 2);
  const int scol = (lane & 3) * 8;
  const unsigned short* gA = A + (size_t)(m0 + srow) * K + scol;
  const unsigned short* gB = Bt + (size_t)(n0 + srow) * K + scol;
  unsigned short* lAw = lA + wid * 1024;
  unsigned short* lBw = lB + wid * 1024;

  f32x4 acc[4][4];
#pragma unroll
  for (int i = 0; i < 4; ++i)
#pragma unroll
    for (int j = 0; j < 4; ++j) acc[i][j] = (f32x4){0.f, 0.f, 0.f, 0.f};

  for (int kt = 0; kt < K; kt += 32) {
    gll16(gA + kt, lAw);
    gll16(gA + (size_t)16 * K + kt, lAw + 512);
    gll16(gB + kt, lBw);
    gll16(gB + (size_t)16 * K + kt, lBw + 512);
    __syncthreads();
    bf16x8 af[4], bfv[4];
#pragma unroll
    for (int i = 0; i < 4; ++i)
      af[i] = *reinterpret_cast<const bf16x8*>(
          &lA[(wr * 64 + i * 16 + fr) * 32 + g * 8]);
#pragma unroll
    for (int j = 0; j < 4; ++j)
      bfv[j] = *reinterpret_cast<const bf16x8*>(
          &lB[(wc * 64 + j * 16 + fr) * 32 + g * 8]);
#pragma unroll
    for (int i = 0; i < 4; ++i)
#pragma unroll
      for (int j = 0; j < 4; ++j)
        acc[i][j] = mfma16(af[i], bfv[j], acc[i][j]);
    __syncthreads();
  }

  const int src = n0 >> 10;
  const float* bp = (MODE == 2) ? b0 : (src == 0 ? b0 : (src == 1 ? b1 : b2));
#pragma unroll
  for (int i = 0; i < 4; ++i)
#pragma unroll
    for (int j = 0; j < 4; ++j)
#pragma unroll
      for (int r = 0; r < 4; ++r) {
        int m = m0 + wr * 64 + i * 16 + g * 4 + r;
        int n = n0 + wc * 64 + j * 16 + fr;
        if (MODE == 2) {
          float val = acc[i][j][r] + bp[n];
          reinterpret_cast<float*>(outp)[(size_t)m * N + n] = val;
        } else {
          int within = n & 1023;
          float val = acc[i][j][r] + bp[within];
          if (src == 0) val *= 0.1803368867f;  // 0.125 * log2(e)
          int b = m >> 11, s = m & 2047;
          int hh = within >> 6, dh = within & 63;
          size_t idx;
          if (src != 2)
            idx = ((size_t)(b * NHEADS + hh) * SEQ + s) * HDIM + dh;
          else
            idx = ((size_t)(b * NHEADS + hh) * HDIM + dh) * SEQ + s;
          reinterpret_cast<unsigned short*>(outp)[(size_t)src * CHELEM + idx] =
              f2bf(val);
        }
      }
}

// Flash attention, SWAPPED-OPERAND (S' = K*Q^T, O^T = V^T*P^T): P is
// lane-local for q = fr -> NO P LDS round-trip, scalar per-lane m/l,
// in-lane P pack with k-permutation pi applied to both PV operands
// (exact). V fragments read as 2x ds_read_b64 at pi-matched swizzled
// chunks. Block-cooperative LDS staging, defer-max, mirror-balanced
// two passes, XCD slab mapping (all round-12/13 proven).
// Q,K: [B,H,S,64] bf16 ; Vt: [B,H,64,S] bf16 ; O: [B,S,1024] bf16
__global__ __launch_bounds__(256) void attn_fwd12(
    const unsigned short* __restrict__ Q,
    const unsigned short* __restrict__ Km,
    const unsigned short* __restrict__ Vt,
    unsigned short* __restrict__ O) {
  const int tid = threadIdx.x;
  const int lane = tid & 63, wid = tid >> 6;
  const int fr = lane & 15, g = lane >> 4;
  // XCD-grouped decode: lin%8 = XCD; 16 blocks per (b,h) slab on one XCD.
  const int lin = blockIdx.x;            // 0..511
  const int c = lin & 7;
  const int t = lin >> 3;                // 0..63
  const int j = t & 15;                  // block's pair index 0..15
  const int sgrp = t >> 4;               // 0..3
  const int slab = sgrp * 8 + c;         // 0..31
  const int b = slab >> 4, h = slab & 15;
  const int bh = b * NHEADS + h;

  __shared__ __align__(16) unsigned short lK[2][4096];   // 2 x 8KB, swizzled
  __shared__ __align__(16) unsigned short lV[2][4096];   // 2 x 8KB, swizzled

  const unsigned short* kptr = Km + (size_t)bh * SEQ * HDIM;
  const unsigned short* vptr = Vt + (size_t)bh * HDIM * SEQ;

  const int sr0 = tid >> 3;              // 0..31
  const int sch = tid & 7;
  const int schx = ((sch ^ (sr0 & 7)) << 3);  // elem offset of 16B chunk
  const int kswz0 = ((g ^ (fr & 7)) << 3);        // ch = g
  const int kswz1 = (((4 + g) ^ (fr & 7)) << 3);  // ch = 4+g
  // V b64 swizzled chunk offsets (elem units), per blk: lo=ch 4b+(g>>1),
  // hi=ch 4b+2+(g>>1); within-chunk half (g&1)*4
  const int g2 = g >> 1, gh = (g & 1) * 4;
  const int vlo0 = (((0 + g2) ^ (fr & 7)) << 3) + gh;   // blk0 lo
  const int vhi0 = (((2 + g2) ^ (fr & 7)) << 3) + gh;   // blk0 hi
  const int vlo1 = (((4 + g2) ^ (fr & 7)) << 3) + gh;   // blk1 lo
  const int vhi1 = (((6 + g2) ^ (fr & 7)) << 3) + gh;   // blk1 hi

#define STAGE(BI, N0)                                                       \
  { gll16(kptr + (size_t)((N0) + sr0) * HDIM + schx, &lK[BI][wid * 512]);   \
    gll16(kptr + (size_t)((N0) + sr0 + 32) * HDIM + schx,                   \
          &lK[BI][2048 + wid * 512]);                                       \
    gll16(vptr + (size_t)sr0 * SEQ + (N0) + schx, &lV[BI][wid * 512]);      \
    gll16(vptr + (size_t)(sr0 + 32) * SEQ + (N0) + schx,                    \
          &lV[BI][2048 + wid * 512]); }

#pragma unroll 1
  for (int pass = 0; pass < 2; ++pass) {
    const int qt = pass ? (124 - 4 * j + wid) : (4 * j + wid);
    const int q0 = qt * 16;
    const int nkt = pass ? (32 - j) : (j + 1);  // same for all 4 waves
    const int qg = q0 + fr;  // this lane's q row

    const unsigned short* qb = Q + ((size_t)bh * SEQ + qg) * HDIM + g * 8;
    bf16x8 qa0 = *reinterpret_cast<const bf16x8*>(qb);        // d 0..31
    bf16x8 qa1 = *reinterpret_cast<const bf16x8*>(qb + 32);   // d 32..63

    f32x4 oacc[4];
#pragma unroll
    for (int i = 0; i < 4; ++i) oacc[i] = (f32x4){0.f, 0.f, 0.f, 0.f};
    float mreg = -3e30f;
    float lrow = 0.f;

    STAGE(0, 0);
    __syncthreads();

    for (int kt = 0; kt < nkt; ++kt) {
      const int bi = kt & 1;
      if (kt + 1 < nkt) STAGE(bi ^ 1, (kt + 1) * 64);
      const int n0 = kt * 64;
      // K fragments as A-operand: lane holds K[cc*16+fr][d = g*8..]
      bf16x8 kf0[4], kf1[4];
#pragma unroll
      for (int cc = 0; cc < 4; ++cc) {
        kf0[cc] = *reinterpret_cast<const bf16x8*>(
            &lK[bi][(cc * 16 + fr) * 64 + kswz0]);
        kf1[cc] = *reinterpret_cast<const bf16x8*>(
            &lK[bi][(cc * 16 + fr) * 64 + kswz1]);
      }
      // S' = K * Q^T: lane (fr,g) holds S'[key=cc*16+g*4+r][q=fr]
      f32x4 s[4];
#pragma unroll
      for (int cc = 0; cc < 4; ++cc) {
        s[cc] = (f32x4){0.f, 0.f, 0.f, 0.f};
        s[cc] = mfma16(kf0[cc], qa0, s[cc]);
        s[cc] = mfma16(kf1[cc], qa1, s[cc]);
      }
      // (last-tile-only) mask; per-lane max (log2 domain, Q pre-scaled)
      float sv[4][4];
      float lmax = -3e30f;
      if (kt == nkt - 1) {
#pragma unroll
        for (int cc = 0; cc < 4; ++cc)
#pragma unroll
          for (int r = 0; r < 4; ++r) {
            sv[cc][r] =
                (n0 + cc * 16 + g * 4 + r <= qg) ? s[cc][r] : -1e30f;
            lmax = fmaxf(lmax, sv[cc][r]);
          }
      } else {
#pragma unroll
        for (int cc = 0; cc < 4; ++cc)
#pragma unroll
          for (int r = 0; r < 4; ++r) {
            sv[cc][r] = s[cc][r];
            lmax = fmaxf(lmax, sv[cc][r]);
          }
      }
      // defer-max: scalar per-lane check; rescale reduces over g (2 shfl)
      if (!__all(lmax - mreg <= 11.5f)) {
        float tm = lmax;
        tm = fmaxf(tm, __shfl_xor(tm, 16, 64));
        tm = fmaxf(tm, __shfl_xor(tm, 32, 64));
        const float mn = fmaxf(mreg, tm);
        const float al = fexp2(mreg - mn);
        mreg = mn;
        lrow *= al;
#pragma unroll
        for (int nf = 0; nf < 4; ++nf) oacc[nf] *= al;
      }
      // P = 2^(sv - m), in-lane pack (pi: slot j<4 -> cc=2blk, j>=4 -> 2blk+1)
      union { __bf16 e[8]; bf16x8 v; } pk0, pk1;
#pragma unroll
      for (int r = 0; r < 4; ++r) {
        float p0 = fexp2(sv[0][r] - mreg);
        float p1 = fexp2(sv[1][r] - mreg);
        float p2 = fexp2(sv[2][r] - mreg);
        float p3 = fexp2(sv[3][r] - mreg);
        lrow += (p0 + p1) + (p2 + p3);
        pk0.e[r] = (__bf16)p0; pk0.e[4 + r] = (__bf16)p1;
        pk1.e[r] = (__bf16)p2; pk1.e[4 + r] = (__bf16)p3;
      }
      // O^T += V^T * P^T with pi-matched V fragments (2x b64 each)
#pragma unroll
      for (int nf = 0; nf < 4; ++nf) {
        const int vrow = (nf * 16 + fr) * 64;
        union { unsigned long long d[2]; bf16x8 v; } v0, v1;
        v0.d[0] = *reinterpret_cast<const unsigned long long*>(&lV[bi][vrow + vlo0]);
        v0.d[1] = *reinterpret_cast<const unsigned long long*>(&lV[bi][vrow + vhi0]);
        v1.d[0] = *reinterpret_cast<const unsigned long long*>(&lV[bi][vrow + vlo1]);
        v1.d[1] = *reinterpret_cast<const unsigned long long*>(&lV[bi][vrow + vhi1]);
        oacc[nf] = mfma16(v0.v, pk0.v, oacc[nf]);
        oacc[nf] = mfma16(v1.v, pk1.v, oacc[nf]);
      }
      __syncthreads();  // staged kt+1 complete; reads of buf bi done
    }

    // epilogue: lsum reduce over g (2 shfl); O^T -> O via direct stores
    float ls = lrow;
    ls += __shfl_xor(ls, 16, 64);
    ls += __shfl_xor(ls, 32, 64);
    const float inv = 1.f / ls;
    const size_t obase = ((size_t)b * SEQ + qg) * D_MODEL + h * HDIM + g * 4;
#pragma unroll
    for (int nf = 0; nf < 4; ++nf) {
      ushort4 o4;
      o4.x = f2bf(oacc[nf][0] * inv);
      o4.y = f2bf(oacc[nf][1] * inv);
      o4.z = f2bf(oacc[nf][2] * inv);
      o4.w = f2bf(oacc[nf][3] * inv);
      *reinterpret_cast<ushort4*>(&O[obase + nf * 16]) = o4;
    }
  }
#undef STAGE
}

extern "C" void kernel_launch(void* const* d_in, const int* in_sizes, int n_in,
                              void* d_out, int out_size, void* d_ws,
                              size_t ws_size, hipStream_t stream) {
  const float* x  = (const float*)d_in[0];
  const float* wq = (const float*)d_in[1];
  const float* bq = (const float*)d_in[2];
  const float* wk = (const float*)d_in[3];
  const float* bk = (const float*)d_in[4];
  const float* wv = (const float*)d_in[5];
  const float* bv = (const float*)d_in[6];
  const float* wo = (const float*)d_in[7];
  const float* bo = (const float*)d_in[8];
  float* out = (float*)d_out;

  char* w = (char*)d_ws;
  unsigned short* xb    = (unsigned short*)w; w += (size_t)MROWS * D_MODEL * 2;
  unsigned short* wqkvb = (unsigned short*)w; w += (size_t)3 * D_MODEL * D_MODEL * 2;
  unsigned short* wob   = (unsigned short*)w; w += (size_t)D_MODEL * D_MODEL * 2;
  unsigned short* Qb    = (unsigned short*)w; w += CHELEM * 2 * 3;  // Q,K,Vt
  unsigned short* Ob    = (unsigned short*)w; w += (size_t)MROWS * D_MODEL * 2;
  unsigned short* Kb  = Qb + CHELEM;
  unsigned short* Vtb = Qb + 2 * CHELEM;

  {
    int n4 = MROWS * D_MODEL / 4;
    cvt_f32_bf16<<<n4 / 256, 256, 0, stream>>>(x, xb, n4);
  }
  {
    int n4 = D_MODEL * D_MODEL / 4;  // 262144 -> 1024 blocks x 4
    cvt_w4<<<dim3(n4 / 256, 4), 256, 0, stream>>>(
        wq, wk, wv, wo, wqkvb, wqkvb + (size_t)D_MODEL * D_MODEL,
        wqkvb + (size_t)2 * D_MODEL * D_MODEL, wob);
  }

  // fused QKV projection: N = 3072
  gemm_bt2<3><<<dim3(3 * D_MODEL / 128, MROWS / 128), 256, 0, stream>>>(
      xb, wqkvb, bq, bk, bv, Qb, MROWS, 3 * D_MODEL, D_MODEL);

  attn_fwd12<<<512, 256, 0, stream>>>(Qb, Kb, Vtb, Ob);

  gemm_bt2<2><<<dim3(D_MODEL / 128, MROWS / 128), 256, 0, stream>>>(
      Ob, wob, bo, bo, bo, out, MROWS, D_MODEL, D_MODEL);
}

// Round 16
// 126.688 us; speedup vs baseline: 1.0740x; 1.0133x over previous
//
#include <hip/hip_runtime.h>
#include <hip/hip_bf16.h>

#define D_MODEL 1024
#define NHEADS  16
#define HDIM    64
#define SEQ     2048
#define BATCH   2
#define MROWS   (BATCH * SEQ)   // 4096
#define CHELEM  ((size_t)BATCH * NHEADS * SEQ * HDIM)  // 4194304

typedef __bf16 bf16x8 __attribute__((ext_vector_type(8)));
typedef float  f32x4  __attribute__((ext_vector_type(4)));

__device__ __forceinline__ unsigned short f2bf(float f) {
  unsigned u = __builtin_bit_cast(unsigned, f);
  return (unsigned short)((u + 0x7fffu + ((u >> 16) & 1u)) >> 16);
}

__device__ __forceinline__ float fexp2(float x) {
#if __has_builtin(__builtin_amdgcn_exp2f)
  return __builtin_amdgcn_exp2f(x);
#else
  return __expf(x * 0.6931471805599453f);
#endif
}

__device__ __forceinline__ f32x4 mfma16(bf16x8 a, bf16x8 b, f32x4 c) {
  return __builtin_amdgcn_mfma_f32_16x16x32_bf16(a, b, c, 0, 0, 0);
}

__device__ __forceinline__ void gll16(const unsigned short* g, unsigned short* l) {
  __builtin_amdgcn_global_load_lds(
      (const __attribute__((address_space(1))) unsigned*)g,
      (__attribute__((address_space(3))) unsigned*)l, 16, 0, 0);
}

__global__ void cvt_f32_bf16(const float* __restrict__ in,
                             unsigned short* __restrict__ out, int n4) {
  int i = blockIdx.x * blockDim.x + threadIdx.x;
  if (i >= n4) return;
  float4 v = reinterpret_cast<const float4*>(in)[i];
  ushort4 o;
  o.x = f2bf(v.x); o.y = f2bf(v.y); o.z = f2bf(v.z); o.w = f2bf(v.w);
  reinterpret_cast<ushort4*>(out)[i] = o;
}

// fused conversion of the 4 weight matrices (saves 3 launches)
__global__ void cvt_w4(const float* __restrict__ s0, const float* __restrict__ s1,
                       const float* __restrict__ s2, const float* __restrict__ s3,
                       unsigned short* __restrict__ d0, unsigned short* __restrict__ d1,
                       unsigned short* __restrict__ d2, unsigned short* __restrict__ d3) {
  int i = blockIdx.x * blockDim.x + threadIdx.x;  // n4 = D*D/4
  const int y = blockIdx.y;
  const float* s = (y == 0) ? s0 : (y == 1) ? s1 : (y == 2) ? s2 : s3;
  unsigned short* d = (y == 0) ? d0 : (y == 1) ? d1 : (y == 2) ? d2 : d3;
  float4 v = reinterpret_cast<const float4*>(s)[i];
  ushort4 o;
  o.x = f2bf(v.x); o.y = f2bf(v.y); o.z = f2bf(v.z); o.w = f2bf(v.w);
  reinterpret_cast<ushort4*>(d)[i] = o;
}

// C = A[M,K] * Bt[N,K]^T + bias  (global_load_lds staging, m97 pattern,
// 16B-chunk XOR swizzle: logical chunk c of row r at physical c^((r>>1)&3)
// -> 8-way ds_read_b128 conflicts become 2-way (free)).
// MODE 2: out f32 row-major [M,N]  (final projection, bias=b0)
// MODE 3: fused QKV: N=3072; chunk 0->Q [B,H,S,64] (PRE-SCALED by
//         0.125*log2e for exp2-domain softmax), 1->K, 2->V^T [B,H,64,S]
template <int MODE>
__global__ __launch_bounds__(256) void gemm_bt2(
    const unsigned short* __restrict__ A,
    const unsigned short* __restrict__ Bt,
    const float* __restrict__ b0, const float* __restrict__ b1,
    const float* __restrict__ b2,
    void* __restrict__ outp, int M, int N, int K) {
  __shared__ __align__(16) unsigned short lA[128 * 32];
  __shared__ __align__(16) unsigned short lB[128 * 32];
  const int tid = threadIdx.x;
  const int m0 = blockIdx.y * 128, n0 = blockIdx.x * 128;
  const int lane = tid & 63, wid = tid >> 6;
  const int wr = wid >> 1, wc = wid & 1;
  const int fr = lane & 15, g = lane >> 4;

  const int srow = wid * 32 + (lane >> 2);
  // pre-swizzled source chunk: physical p = lane&3 holds logical p ^ s,
  // s = (srow>>1)&3 = (lane>>3)&3  (wid*16 and +16 rows are 0 mod 4)
  const int scol = ((lane & 3) ^ ((lane >> 3) & 3)) * 8;
  const unsigned short* gA = A + (size_t)(m0 + srow) * K + scol;
  const unsigned short* gB = Bt + (size_t)(n0 + srow) * K + scol;
  unsigned short* lAw = lA + wid * 1024;
  unsigned short* lBw = lB + wid * 1024;

  // read-side swizzle: logical chunk g of row (..+fr) at g ^ ((fr>>1)&3)
  const int rswz = (g ^ ((fr >> 1) & 3)) * 8;

  f32x4 acc[4][4];
#pragma unroll
  for (int i = 0; i < 4; ++i)
#pragma unroll
    for (int j = 0; j < 4; ++j) acc[i][j] = (f32x4){0.f, 0.f, 0.f, 0.f};

  for (int kt = 0; kt < K; kt += 32) {
    gll16(gA + kt, lAw);
    gll16(gA + (size_t)16 * K + kt, lAw + 512);
    gll16(gB + kt, lBw);
    gll16(gB + (size_t)16 * K + kt, lBw + 512);
    __syncthreads();
    bf16x8 af[4], bfv[4];
#pragma unroll
    for (int i = 0; i < 4; ++i)
      af[i] = *reinterpret_cast<const bf16x8*>(
          &lA[(wr * 64 + i * 16 + fr) * 32 + rswz]);
#pragma unroll
    for (int j = 0; j < 4; ++j)
      bfv[j] = *reinterpret_cast<const bf16x8*>(
          &lB[(wc * 64 + j * 16 + fr) * 32 + rswz]);
#pragma unroll
    for (int i = 0; i < 4; ++i)
#pragma unroll
      for (int j = 0; j < 4; ++j)
        acc[i][j] = mfma16(af[i], bfv[j], acc[i][j]);
    __syncthreads();
  }

  const int src = n0 >> 10;
  const float* bp = (MODE == 2) ? b0 : (src == 0 ? b0 : (src == 1 ? b1 : b2));
#pragma unroll
  for (int i = 0; i < 4; ++i)
#pragma unroll
    for (int j = 0; j < 4; ++j)
#pragma unroll
      for (int r = 0; r < 4; ++r) {
        int m = m0 + wr * 64 + i * 16 + g * 4 + r;
        int n = n0 + wc * 64 + j * 16 + fr;
        if (MODE == 2) {
          float val = acc[i][j][r] + bp[n];
          reinterpret_cast<float*>(outp)[(size_t)m * N + n] = val;
        } else {
          int within = n & 1023;
          float val = acc[i][j][r] + bp[within];
          if (src == 0) val *= 0.1803368867f;  // 0.125 * log2(e)
          int b = m >> 11, s = m & 2047;
          int hh = within >> 6, dh = within & 63;
          size_t idx;
          if (src != 2)
            idx = ((size_t)(b * NHEADS + hh) * SEQ + s) * HDIM + dh;
          else
            idx = ((size_t)(b * NHEADS + hh) * HDIM + dh) * SEQ + s;
          reinterpret_cast<unsigned short*>(outp)[(size_t)src * CHELEM + idx] =
              f2bf(val);
        }
      }
}

// Flash attention, SWAPPED-OPERAND (S' = K*Q^T, O^T = V^T*P^T): P is
// lane-local for q = fr -> NO P LDS round-trip, scalar per-lane m/l,
// in-lane P pack with k-permutation pi applied to both PV operands
// (exact). V fragments read as 2x ds_read_b64 at pi-matched swizzled
// chunks. Block-cooperative LDS staging, defer-max, mirror-balanced
// two passes, XCD slab mapping (all round-12/13/15 proven).
// Q,K: [B,H,S,64] bf16 ; Vt: [B,H,64,S] bf16 ; O: [B,S,1024] bf16
__global__ __launch_bounds__(256) void attn_fwd12(
    const unsigned short* __restrict__ Q,
    const unsigned short* __restrict__ Km,
    const unsigned short* __restrict__ Vt,
    unsigned short* __restrict__ O) {
  const int tid = threadIdx.x;
  const int lane = tid & 63, wid = tid >> 6;
  const int fr = lane & 15, g = lane >> 4;
  // XCD-grouped decode: lin%8 = XCD; 16 blocks per (b,h) slab on one XCD.
  const int lin = blockIdx.x;            // 0..511
  const int c = lin & 7;
  const int t = lin >> 3;                // 0..63
  const int j = t & 15;                  // block's pair index 0..15
  const int sgrp = t >> 4;               // 0..3
  const int slab = sgrp * 8 + c;         // 0..31
  const int b = slab >> 4, h = slab & 15;
  const int bh = b * NHEADS + h;

  __shared__ __align__(16) unsigned short lK[2][4096];   // 2 x 8KB, swizzled
  __shared__ __align__(16) unsigned short lV[2][4096];   // 2 x 8KB, swizzled

  const unsigned short* kptr = Km + (size_t)bh * SEQ * HDIM;
  const unsigned short* vptr = Vt + (size_t)bh * HDIM * SEQ;

  const int sr0 = tid >> 3;              // 0..31
  const int sch = tid & 7;
  const int schx = ((sch ^ (sr0 & 7)) << 3);  // elem offset of 16B chunk
  const int kswz0 = ((g ^ (fr & 7)) << 3);        // ch = g
  const int kswz1 = (((4 + g) ^ (fr & 7)) << 3);  // ch = 4+g
  // V b64 swizzled chunk offsets (elem units), per blk: lo=ch 4b+(g>>1),
  // hi=ch 4b+2+(g>>1); within-chunk half (g&1)*4
  const int g2 = g >> 1, gh = (g & 1) * 4;
  const int vlo0 = (((0 + g2) ^ (fr & 7)) << 3) + gh;   // blk0 lo
  const int vhi0 = (((2 + g2) ^ (fr & 7)) << 3) + gh;   // blk0 hi
  const int vlo1 = (((4 + g2) ^ (fr & 7)) << 3) + gh;   // blk1 lo
  const int vhi1 = (((6 + g2) ^ (fr & 7)) << 3) + gh;   // blk1 hi

#define STAGE(BI, N0)                                                       \
  { gll16(kptr + (size_t)((N0) + sr0) * HDIM + schx, &lK[BI][wid * 512]);   \
    gll16(kptr + (size_t)((N0) + sr0 + 32) * HDIM + schx,                   \
          &lK[BI][2048 + wid * 512]);                                       \
    gll16(vptr + (size_t)sr0 * SEQ + (N0) + schx, &lV[BI][wid * 512]);      \
    gll16(vptr + (size_t)(sr0 + 32) * SEQ + (N0) + schx,                    \
          &lV[BI][2048 + wid * 512]); }

#pragma unroll 1
  for (int pass = 0; pass < 2; ++pass) {
    const int qt = pass ? (124 - 4 * j + wid) : (4 * j + wid);
    const int q0 = qt * 16;
    const int nkt = pass ? (32 - j) : (j + 1);  // same for all 4 waves
    const int qg = q0 + fr;  // this lane's q row

    const unsigned short* qb = Q + ((size_t)bh * SEQ + qg) * HDIM + g * 8;
    bf16x8 qa0 = *reinterpret_cast<const bf16x8*>(qb);        // d 0..31
    bf16x8 qa1 = *reinterpret_cast<const bf16x8*>(qb + 32);   // d 32..63

    f32x4 oacc[4];
#pragma unroll
    for (int i = 0; i < 4; ++i) oacc[i] = (f32x4){0.f, 0.f, 0.f, 0.f};
    float mreg = -3e30f;
    float lrow = 0.f;

    STAGE(0, 0);
    __syncthreads();

    for (int kt = 0; kt < nkt; ++kt) {
      const int bi = kt & 1;
      if (kt + 1 < nkt) STAGE(bi ^ 1, (kt + 1) * 64);
      const int n0 = kt * 64;
      // K fragments as A-operand: lane holds K[cc*16+fr][d = g*8..]
      bf16x8 kf0[4], kf1[4];
#pragma unroll
      for (int cc = 0; cc < 4; ++cc) {
        kf0[cc] = *reinterpret_cast<const bf16x8*>(
            &lK[bi][(cc * 16 + fr) * 64 + kswz0]);
        kf1[cc] = *reinterpret_cast<const bf16x8*>(
            &lK[bi][(cc * 16 + fr) * 64 + kswz1]);
      }
      // S' = K * Q^T: lane (fr,g) holds S'[key=cc*16+g*4+r][q=fr]
      f32x4 s[4];
#pragma unroll
      for (int cc = 0; cc < 4; ++cc) {
        s[cc] = (f32x4){0.f, 0.f, 0.f, 0.f};
        s[cc] = mfma16(kf0[cc], qa0, s[cc]);
        s[cc] = mfma16(kf1[cc], qa1, s[cc]);
      }
      // (last-tile-only) mask; per-lane max (log2 domain, Q pre-scaled)
      float sv[4][4];
      float lmax = -3e30f;
      if (kt == nkt - 1) {
#pragma unroll
        for (int cc = 0; cc < 4; ++cc)
#pragma unroll
          for (int r = 0; r < 4; ++r) {
            sv[cc][r] =
                (n0 + cc * 16 + g * 4 + r <= qg) ? s[cc][r] : -1e30f;
            lmax = fmaxf(lmax, sv[cc][r]);
          }
      } else {
#pragma unroll
        for (int cc = 0; cc < 4; ++cc)
#pragma unroll
          for (int r = 0; r < 4; ++r) {
            sv[cc][r] = s[cc][r];
            lmax = fmaxf(lmax, sv[cc][r]);
          }
      }
      // defer-max: scalar per-lane check; rescale reduces over g (2 shfl)
      if (!__all(lmax - mreg <= 11.5f)) {
        float tm = lmax;
        tm = fmaxf(tm, __shfl_xor(tm, 16, 64));
        tm = fmaxf(tm, __shfl_xor(tm, 32, 64));
        const float mn = fmaxf(mreg, tm);
        const float al = fexp2(mreg - mn);
        mreg = mn;
        lrow *= al;
#pragma unroll
        for (int nf = 0; nf < 4; ++nf) oacc[nf] *= al;
      }
      // P = 2^(sv - m), in-lane pack (pi: slot j<4 -> cc=2blk, j>=4 -> 2blk+1)
      union { __bf16 e[8]; bf16x8 v; } pk0, pk1;
#pragma unroll
      for (int r = 0; r < 4; ++r) {
        float p0 = fexp2(sv[0][r] - mreg);
        float p1 = fexp2(sv[1][r] - mreg);
        float p2 = fexp2(sv[2][r] - mreg);
        float p3 = fexp2(sv[3][r] - mreg);
        lrow += (p0 + p1) + (p2 + p3);
        pk0.e[r] = (__bf16)p0; pk0.e[4 + r] = (__bf16)p1;
        pk1.e[r] = (__bf16)p2; pk1.e[4 + r] = (__bf16)p3;
      }
      // O^T += V^T * P^T with pi-matched V fragments (2x b64 each)
#pragma unroll
      for (int nf = 0; nf < 4; ++nf) {
        const int vrow = (nf * 16 + fr) * 64;
        union { unsigned long long d[2]; bf16x8 v; } v0, v1;
        v0.d[0] = *reinterpret_cast<const unsigned long long*>(&lV[bi][vrow + vlo0]);
        v0.d[1] = *reinterpret_cast<const unsigned long long*>(&lV[bi][vrow + vhi0]);
        v1.d[0] = *reinterpret_cast<const unsigned long long*>(&lV[bi][vrow + vlo1]);
        v1.d[1] = *reinterpret_cast<const unsigned long long*>(&lV[bi][vrow + vhi1]);
        oacc[nf] = mfma16(v0.v, pk0.v, oacc[nf]);
        oacc[nf] = mfma16(v1.v, pk1.v, oacc[nf]);
      }
      __syncthreads();  // staged kt+1 complete; reads of buf bi done
    }

    // epilogue: lsum reduce over g (2 shfl); O^T -> O via direct stores
    float ls = lrow;
    ls += __shfl_xor(ls, 16, 64);
    ls += __shfl_xor(ls, 32, 64);
    const float inv = 1.f / ls;
    const size_t obase = ((size_t)b * SEQ + qg) * D_MODEL + h * HDIM + g * 4;
#pragma unroll
    for (int nf = 0; nf < 4; ++nf) {
      ushort4 o4;
      o4.x = f2bf(oacc[nf][0] * inv);
      o4.y = f2bf(oacc[nf][1] * inv);
      o4.z = f2bf(oacc[nf][2] * inv);
      o4.w = f2bf(oacc[nf][3] * inv);
      *reinterpret_cast<ushort4*>(&O[obase + nf * 16]) = o4;
    }
  }
#undef STAGE
}

extern "C" void kernel_launch(void* const* d_in, const int* in_sizes, int n_in,
                              void* d_out, int out_size, void* d_ws,
                              size_t ws_size, hipStream_t stream) {
  const float* x  = (const float*)d_in[0];
  const float* wq = (const float*)d_in[1];
  const float* bq = (const float*)d_in[2];
  const float* wk = (const float*)d_in[3];
  const float* bk = (const float*)d_in[4];
  const float* wv = (const float*)d_in[5];
  const float* bv = (const float*)d_in[6];
  const float* wo = (const float*)d_in[7];
  const float* bo = (const float*)d_in[8];
  float* out = (float*)d_out;

  char* w = (char*)d_ws;
  unsigned short* xb    = (unsigned short*)w; w += (size_t)MROWS * D_MODEL * 2;
  unsigned short* wqkvb = (unsigned short*)w; w += (size_t)3 * D_MODEL * D_MODEL * 2;
  unsigned short* wob   = (unsigned short*)w; w += (size_t)D_MODEL * D_MODEL * 2;
  unsigned short* Qb    = (unsigned short*)w; w += CHELEM * 2 * 3;  // Q,K,Vt
  unsigned short* Ob    = (unsigned short*)w; w += (size_t)MROWS * D_MODEL * 2;
  unsigned short* Kb  = Qb + CHELEM;
  unsigned short* Vtb = Qb + 2 * CHELEM;

  {
    int n4 = MROWS * D_MODEL / 4;
    cvt_f32_bf16<<<n4 / 256, 256, 0, stream>>>(x, xb, n4);
  }
  {
    int n4 = D_MODEL * D_MODEL / 4;  // 262144 -> 1024 blocks x 4
    cvt_w4<<<dim3(n4 / 256, 4), 256, 0, stream>>>(
        wq, wk, wv, wo, wqkvb, wqkvb + (size_t)D_MODEL * D_MODEL,
        wqkvb + (size_t)2 * D_MODEL * D_MODEL, wob);
  }

  // fused QKV projection: N = 3072
  gemm_bt2<3><<<dim3(3 * D_MODEL / 128, MROWS / 128), 256, 0, stream>>>(
      xb, wqkvb, bq, bk, bv, Qb, MROWS, 3 * D_MODEL, D_MODEL);

  attn_fwd12<<<512, 256, 0, stream>>>(Qb, Kb, Vtb, Ob);

  gemm_bt2<2><<<dim3(D_MODEL / 128, MROWS / 128), 256, 0, stream>>>(
      Ob, wob, bo, bo, bo, out, MROWS, D_MODEL, D_MODEL);
}